// Round 4
// baseline (15.013 us; speedup 1.0000x reference)
//
#include <hip/hip_runtime.h>
#include <hip/hip_bf16.h>

// Embedding gather: out[t, :] = embeddings[x[t], :]
// x: int32 [8192], embeddings: fp32 [32000, 1024], out: fp32 [8192, 1024]
// 8 rows per block, 256 threads: each thread moves one 16B vector per row,
// all 8 gather loads issued back-to-back for deep memory-level parallelism.

typedef float fx4 __attribute__((ext_vector_type(4)));

#define EMBED_DIM 1024
#define VEC4_PER_ROW (EMBED_DIM / 4)   // 256
#define ROWS_PER_BLOCK 8

__global__ __launch_bounds__(256) void embedding_gather_kernel(
    const int* __restrict__ x,
    const fx4* __restrict__ emb,      // [vocab, 256] as fx4
    fx4* __restrict__ out,            // [ntok, 256] as fx4
    int ntok)
{
    int base = blockIdx.x * ROWS_PER_BLOCK;
    int col = threadIdx.x;            // 0..255, one 16B vector each

    int idx[ROWS_PER_BLOCK];
#pragma unroll
    for (int i = 0; i < ROWS_PER_BLOCK; ++i) {
        int r = base + i;
        idx[i] = (r < ntok) ? x[r] : 0;   // uniform scalar loads
    }

    fx4 v[ROWS_PER_BLOCK];
#pragma unroll
    for (int i = 0; i < ROWS_PER_BLOCK; ++i) {
        v[i] = emb[(size_t)idx[i] * VEC4_PER_ROW + col];   // 8 loads in flight
    }

#pragma unroll
    for (int i = 0; i < ROWS_PER_BLOCK; ++i) {
        int r = base + i;
        if (r < ntok) {
            // non-temporal: write-once output, keep table rows cache-resident
            __builtin_nontemporal_store(v[i], &out[(size_t)r * VEC4_PER_ROW + col]);
        }
    }
}

extern "C" void kernel_launch(void* const* d_in, const int* in_sizes, int n_in,
                              void* d_out, int out_size, void* d_ws, size_t ws_size,
                              hipStream_t stream) {
    const int* x = (const int*)d_in[0];
    const fx4* emb = (const fx4*)d_in[1];
    fx4* out = (fx4*)d_out;

    int ntok = in_sizes[0];           // 8192
    int nblocks = (ntok + ROWS_PER_BLOCK - 1) / ROWS_PER_BLOCK;   // 1024
    embedding_gather_kernel<<<dim3(nblocks), dim3(256), 0, stream>>>(x, emb, out, ntok);
}